// Round 3
// baseline (1366.024 us; speedup 1.0000x reference)
//
#include <hip/hip_runtime.h>
#include <hip/hip_bf16.h>
#include <math.h>

// Problem constants
#define Bsz 2048
#define T1  9      // T-1
#define Hs  512
#define IN2 15

typedef __bf16 bf16x8 __attribute__((ext_vector_type(8)));
typedef float  f32x4  __attribute__((ext_vector_type(4)));
typedef __hip_bfloat16 bf16;

// ---------------------------------------------------------------------------
// Algebra (verified: rounds 1-2 passed, round-2 absmax 0.0):
//  * enc softmax over features invariant to (h@Wh+s@Ws) scalar => a1/a2
//    constant over time; Wh/Ws dead.
//  * dec attention: score = Xe.v + const(b), v = W2@W1x => beta/context
//    constant across decoder steps; rank-1 y_tilde term folded into epilogue.
// This round: bf16x2 (A.W ~= Ahi.Whi + Ahi.Wlo; dropped-term error ~3e-4 on
// gates, ~2e-4 on output, budget 5.9e-3) + single-barrier double-buffered
// LDS pipeline (writes overlap MFMA, depth-2 global prefetch).
// Weight layout n' = (j/16)*64 + g*16 + (j%16): a 64-wide wave tile holds all
// 4 gates for 16 j's -> fully in-register gate epilogue.
// ---------------------------------------------------------------------------

#define BMT 128   // rows (batch) per block
#define BNP 128   // n' cols per block
#define LDK 40    // padded LDS row length in bf16 (32 data + 8 pad -> 80B)

struct GA {
  const bf16* Ahi;   // B x HG   activations (hi)
  const bf16* Axhi;  // B x 16   x-part for this t (enc) or null
  const bf16* Whi;   // 4HG x Kpad, n'-ordered
  const bf16* Wlo;
  const float* bsum; // 4HG, n'-ordered (bih+bhh)
  const float* wihp; // 4HG, n'-ordered rank-1 weights (dec) or null
  const float* ytp;  // rank-1 activation column y_tilde (dec) or null
  float* c;          // B x HG cell state (in/out)
  bf16* Hhi;         // B x HG h out
  float* hf;         // optional fp32 h out (Xe slice / final d) or null
  int hf_stride;
  int ytstride;
};

template<int HG, int KPAD, bool HAS_X, int ZD>
__global__ __launch_bounds__(256, 2)
void lstm2_k(GA a0, GA a1) {
  constexpr int KT = KPAD / 32;
  constexpr int GX = (4 * HG) / BNP;
  constexpr int GY = Bsz / BMT;
  constexpr int NWG = GX * GY * ZD;
  constexpr int Q = NWG / 8;

  __shared__ __align__(16) unsigned short As[2][BMT * LDK];
  __shared__ __align__(16) unsigned short Bh[2][BMT * LDK];
  __shared__ __align__(16) unsigned short Bl[2][BMT * LDK];

  const int tid = threadIdx.x;
  // bijective XCD swizzle (NWG % 8 == 0); mb fastest -> same-XCD blocks share
  // the weight panel in that XCD's L2.
  const int orig = blockIdx.x + GX * (blockIdx.y + GY * blockIdx.z);
  const int swz = (orig & 7) * Q + (orig >> 3);
  const GA A = (ZD == 2 && swz >= GX * GY) ? a1 : a0;
  const int rem = (ZD == 2) ? (swz & (GX * GY - 1)) : swz;
  const int nb = rem / GY;
  const int mb = rem % GY;
  const int m0 = mb * BMT, n0 = nb * BNP;

  // staging map: kcb = 8-elem column offset (constant/thread), rows ra, ra+64
  const int kcb = (tid & 3) * 8;
  const int ra = tid >> 2;

  uint4 sv[6];
  auto stage_load = [&](int kt) {
    const int ke = kt * 32 + kcb;
    if (!HAS_X || ke < HG) {
      const size_t ag = (size_t)(m0 + ra) * HG + ke;
      sv[0] = *reinterpret_cast<const uint4*>(A.Ahi + ag);
      sv[1] = *reinterpret_cast<const uint4*>(A.Ahi + ag + (size_t)64 * HG);
    } else {
      uint4 z; z.x = z.y = z.z = z.w = 0u;
      if (ke < HG + 16) {
        sv[0] = *reinterpret_cast<const uint4*>(A.Axhi + (size_t)(m0 + ra) * 16 + (ke - HG));
        sv[1] = *reinterpret_cast<const uint4*>(A.Axhi + (size_t)(m0 + ra + 64) * 16 + (ke - HG));
      } else { sv[0] = z; sv[1] = z; }
    }
    const size_t bg = (size_t)(n0 + ra) * KPAD + ke;
    sv[2] = *reinterpret_cast<const uint4*>(A.Whi + bg);
    sv[3] = *reinterpret_cast<const uint4*>(A.Whi + bg + (size_t)64 * KPAD);
    sv[4] = *reinterpret_cast<const uint4*>(A.Wlo + bg);
    sv[5] = *reinterpret_cast<const uint4*>(A.Wlo + bg + (size_t)64 * KPAD);
  };
  auto stage_write = [&](int p) {
    unsigned short* ap = &As[p][ra * LDK + kcb];
    *reinterpret_cast<uint4*>(ap) = sv[0];
    *reinterpret_cast<uint4*>(ap + 64 * LDK) = sv[1];
    unsigned short* hp = &Bh[p][ra * LDK + kcb];
    *reinterpret_cast<uint4*>(hp) = sv[2];
    *reinterpret_cast<uint4*>(hp + 64 * LDK) = sv[3];
    unsigned short* lp = &Bl[p][ra * LDK + kcb];
    *reinterpret_cast<uint4*>(lp) = sv[4];
    *reinterpret_cast<uint4*>(lp + 64 * LDK) = sv[5];
  };

  const int lane = tid & 63;
  const int wv = tid >> 6;
  const int wr = wv >> 1, wc = wv & 1;  // 2x2 wave grid, 64x64 each
  const int l15 = lane & 15;
  const int lk = (lane >> 4) * 8;

  int aoff[4], boff[4];
#pragma unroll
  for (int mi = 0; mi < 4; ++mi) aoff[mi] = (wr * 64 + mi * 16 + l15) * LDK + lk;
#pragma unroll
  for (int ni = 0; ni < 4; ++ni) boff[ni] = (wc * 64 + ni * 16 + l15) * LDK + lk;

  f32x4 acc[4][4] = {};

  stage_load(0);
  stage_write(0);
  stage_load(1);

  for (int kt = 0; kt < KT; ++kt) {
    __syncthreads();
    const int p = kt & 1;
    bf16x8 ah[4], bhv[4], blv[4];
#pragma unroll
    for (int mi = 0; mi < 4; ++mi)
      ah[mi] = __builtin_bit_cast(bf16x8, *reinterpret_cast<const uint4*>(&As[p][aoff[mi]]));
#pragma unroll
    for (int ni = 0; ni < 4; ++ni) {
      bhv[ni] = __builtin_bit_cast(bf16x8, *reinterpret_cast<const uint4*>(&Bh[p][boff[ni]]));
      blv[ni] = __builtin_bit_cast(bf16x8, *reinterpret_cast<const uint4*>(&Bl[p][boff[ni]]));
    }
#pragma unroll
    for (int ni = 0; ni < 4; ++ni)
#pragma unroll
      for (int mi = 0; mi < 4; ++mi)
        acc[mi][ni] = __builtin_amdgcn_mfma_f32_16x16x32_bf16(ah[mi], bhv[ni], acc[mi][ni], 0, 0, 0);
#pragma unroll
    for (int ni = 0; ni < 4; ++ni)
#pragma unroll
      for (int mi = 0; mi < 4; ++mi)
        acc[mi][ni] = __builtin_amdgcn_mfma_f32_16x16x32_bf16(ah[mi], blv[ni], acc[mi][ni], 0, 0, 0);
    if (kt + 1 < KT) {
      stage_write(p ^ 1);                 // overlaps other waves' MFMA
      if (kt + 2 < KT) stage_load(kt + 2);  // full iteration of HBM latency hiding
    }
  }

  // Epilogue: ni == gate g; j = nb*32 + wc*16 + l15
  const int j = nb * 32 + wc * 16 + l15;
  const int npb = nb * 128 + wc * 64 + l15;
  const float bs0 = A.bsum[npb], bs1 = A.bsum[npb + 16];
  const float bs2 = A.bsum[npb + 32], bs3 = A.bsum[npb + 48];
  float w0 = 0.f, w1 = 0.f, w2 = 0.f, w3 = 0.f;
  if (!HAS_X) {
    w0 = A.wihp[npb]; w1 = A.wihp[npb + 16];
    w2 = A.wihp[npb + 32]; w3 = A.wihp[npb + 48];
  }
#pragma unroll
  for (int mi = 0; mi < 4; ++mi) {
#pragma unroll
    for (int r = 0; r < 4; ++r) {
      const int rowl = wr * 64 + mi * 16 + (lane >> 4) * 4 + r;
      const size_t rowg = m0 + rowl;
      float gi = acc[mi][0][r] + bs0;
      float gf = acc[mi][1][r] + bs1;
      float gg = acc[mi][2][r] + bs2;
      float go = acc[mi][3][r] + bs3;
      if (!HAS_X) {
        const float yv = A.ytp[rowg * A.ytstride];
        gi += yv * w0; gf += yv * w1; gg += yv * w2; go += yv * w3;
      }
      const float i_ = 1.f / (1.f + __expf(-gi));
      const float f_ = 1.f / (1.f + __expf(-gf));
      const float tg = __expf(2.f * gg);
      const float g_ = (tg - 1.f) / (tg + 1.f);
      const float o_ = 1.f / (1.f + __expf(-go));
      const size_t idx = rowg * HG + j;
      const float cn = f_ * A.c[idx] + i_ * g_;
      A.c[idx] = cn;
      const float tc = __expf(2.f * cn);
      const float hn = o_ * (tc - 1.f) / (tc + 1.f);
      A.Hhi[idx] = __float2bfloat16(hn);
      if (A.hf) A.hf[rowg * A.hf_stride + j] = hn;
    }
  }
}

// Build composite weights in n'-interleaved order, split hi/lo; bsum; wihp.
// One thread per (np, 8-wide k chunk).
__global__ void build_w_k(const float* __restrict__ Whh, const float* __restrict__ Wih,
                          const float* __restrict__ bih, const float* __restrict__ bhh,
                          bf16* __restrict__ Whi, bf16* __restrict__ Wlo,
                          float* __restrict__ bsum, float* __restrict__ wihp,
                          int HG, int nx, int Kpad) {
  const int chunks = Kpad >> 3;
  const int idx = blockIdx.x * 256 + threadIdx.x;
  if (idx >= 4 * HG * chunks) return;
  const int np = idx / chunks;
  const int k0 = (idx - np * chunks) << 3;
  const int g = (np >> 4) & 3;
  const int jj = ((np >> 6) << 4) + (np & 15);
  const int norig = g * HG + jj;
  float v[8];
  if (k0 + 8 <= HG) {
    const float4* s = reinterpret_cast<const float4*>(Whh + (size_t)norig * HG + k0);
    float4 v0 = s[0], v1 = s[1];
    v[0] = v0.x; v[1] = v0.y; v[2] = v0.z; v[3] = v0.w;
    v[4] = v1.x; v[5] = v1.y; v[6] = v1.z; v[7] = v1.w;
  } else {
#pragma unroll
    for (int u = 0; u < 8; ++u) {
      const int k = k0 + u;
      v[u] = (k < HG) ? Whh[(size_t)norig * HG + k]
                      : ((k - HG < nx) ? Wih[(size_t)norig * nx + (k - HG)] : 0.f);
    }
  }
  unsigned short hh[8], ll[8];
#pragma unroll
  for (int u = 0; u < 8; ++u) {
    const bf16 h = __float2bfloat16(v[u]);
    const bf16 l = __float2bfloat16(v[u] - __bfloat162float(h));
    hh[u] = *reinterpret_cast<const unsigned short*>(&h);
    ll[u] = *reinterpret_cast<const unsigned short*>(&l);
  }
  const size_t off = (size_t)np * Kpad + k0;
  *reinterpret_cast<uint4*>((unsigned short*)Whi + off) = *reinterpret_cast<uint4*>(hh);
  *reinterpret_cast<uint4*>((unsigned short*)Wlo + off) = *reinterpret_cast<uint4*>(ll);
  if (k0 == 0) {
    bsum[np] = bih[norig] + bhh[norig];
    if (wihp) wihp[np] = Wih[norig];  // dec: Wih is (8H,1)
  }
}

// Per-batch encoder attention weights (time-invariant) -> x_tilde tables.
__global__ void prep_attn_k(const float* __restrict__ X, const float* __restrict__ yp,
                            const float* __restrict__ encW, const float* __restrict__ encb,
                            bf16* __restrict__ x1h, bf16* __restrict__ x2h) {
  const int b = blockIdx.x;
  const int tid = threadIdx.x;  // 64
  __shared__ float wf[T1], ypb[T1];
  __shared__ float s1[16], s2[IN2], e1[16], e2[IN2];
  if (tid < T1) {
    wf[tid] = encW[2 * Hs + tid];
    ypb[tid] = yp[(size_t)b * T1 + tid];
  }
  __syncthreads();
  const float bb = encb[0];
  if (tid < 16) {
    float acc = bb;
    for (int t = 0; t < T1; ++t) {
      float xv = (tid < IN2) ? X[(size_t)b * (T1 * IN2) + t * IN2 + tid] : ypb[t];
      acc += xv * wf[t];
    }
    s1[tid] = acc;
  } else if (tid < 16 + IN2) {
    const int k = tid - 16;
    float acc = bb;
    for (int t = 0; t < T1; ++t)
      acc += X[(size_t)b * (T1 * IN2) + t * IN2 + k] * ypb[t] * wf[t];
    s2[k] = acc;
  }
  __syncthreads();
  if (tid < 16) {
    float m = -1e30f;
    for (int k = 0; k < 16; ++k) m = fmaxf(m, s1[k]);
    e1[tid] = expf(s1[tid] - m);
  } else if (tid < 16 + IN2) {
    const int k = tid - 16;
    float m = -1e30f;
    for (int kk = 0; kk < IN2; ++kk) m = fmaxf(m, s2[kk]);
    e2[k] = expf(s2[k] - m);
  }
  __syncthreads();
  if (tid < 16) {
    float sum = 0.f;
    for (int k = 0; k < 16; ++k) sum += e1[k];
    const float a = e1[tid] / sum;
    for (int t = 0; t < T1; ++t) {
      float xv = (tid < IN2) ? X[(size_t)b * (T1 * IN2) + t * IN2 + tid] : ypb[t];
      x1h[((size_t)t * Bsz + b) * 16 + tid] = __float2bfloat16(a * xv);
    }
  } else if (tid < 16 + IN2) {
    const int k = tid - 16;
    float sum = 0.f;
    for (int kk = 0; kk < IN2; ++kk) sum += e2[kk];
    const float a = e2[k] / sum;
    for (int t = 0; t < T1; ++t)
      x2h[((size_t)t * Bsz + b) * 16 + k] =
          __float2bfloat16(a * X[(size_t)b * (T1 * IN2) + t * IN2 + k] * ypb[t]);
  } else if (tid == 31) {
    const bf16 z = __float2bfloat16(0.f);
    for (int t = 0; t < T1; ++t) x2h[((size_t)t * Bsz + b) * 16 + 15] = z;
  }
}

// v[dd] = sum_h dec_attn2_W[0,h] * dec_attn1_W[h, 4H+dd]
__global__ void prep_v_k(const float* __restrict__ A1W, const float* __restrict__ A2W,
                         float* __restrict__ v) {
  const int dd = blockIdx.x * blockDim.x + threadIdx.x;
  float acc = 0.f;
  for (int h = 0; h < Hs; ++h) acc += A2W[h] * A1W[(size_t)h * (6 * Hs) + 4 * Hs + dd];
  v[dd] = acc;
}

// Decoder attention (step-invariant): softmax over t, context, y_tilde table.
__global__ void dec_ctx_k(const float* __restrict__ Xe, const float* __restrict__ v,
                          const float* __restrict__ yp, const float* __restrict__ fcW,
                          const float* __restrict__ fcb,
                          float* __restrict__ ctx, float* __restrict__ yt) {
  const int b = blockIdx.x;
  const int tid = threadIdx.x;  // 256
  const float* xb = Xe + (size_t)b * (T1 * 2 * Hs);
  float s[T1];
#pragma unroll
  for (int t = 0; t < T1; ++t) s[t] = 0.f;
  for (int dd = tid; dd < 2 * Hs; dd += 256) {
    const float vv = v[dd];
#pragma unroll
    for (int t = 0; t < T1; ++t) s[t] += xb[t * 2 * Hs + dd] * vv;
  }
  __shared__ float red[256];
  __shared__ float score[T1];
  for (int t = 0; t < T1; ++t) {
    red[tid] = s[t];
    __syncthreads();
    for (int off = 128; off > 0; off >>= 1) {
      if (tid < off) red[tid] += red[tid + off];
      __syncthreads();
    }
    if (tid == 0) score[t] = red[0];
    __syncthreads();
  }
  float mx = -1e30f;
#pragma unroll
  for (int t = 0; t < T1; ++t) mx = fmaxf(mx, score[t]);
  float e[T1];
  float sum = 0.f;
#pragma unroll
  for (int t = 0; t < T1; ++t) { e[t] = expf(score[t] - mx); sum += e[t]; }
  const float inv = 1.f / sum;
  float fcacc = 0.f;
  for (int dd = tid; dd < 2 * Hs; dd += 256) {
    float c = 0.f;
#pragma unroll
    for (int t = 0; t < T1; ++t) c += e[t] * xb[t * 2 * Hs + dd];
    c *= inv;
    ctx[(size_t)b * 2 * Hs + dd] = c;
    fcacc += c * fcW[dd];
  }
  red[tid] = fcacc;
  __syncthreads();
  for (int off = 128; off > 0; off >>= 1) {
    if (tid < off) red[tid] += red[tid + off];
    __syncthreads();
  }
  const float cf = red[0] + fcb[0];
  if (tid < T1) yt[(size_t)b * T1 + tid] = cf + yp[(size_t)b * T1 + tid] * fcW[2 * Hs];
}

__global__ void final_out_k(const float* __restrict__ dfin, const float* __restrict__ ctx,
                            const float* __restrict__ Wfin, const float* __restrict__ bfin,
                            float* __restrict__ out) {
  const int b = blockIdx.x;
  const int tid = threadIdx.x;  // 256
  float acc = 0.f;
  for (int jj = tid; jj < 2 * Hs; jj += 256) acc += dfin[(size_t)b * 2 * Hs + jj] * Wfin[jj];
  for (int jj = tid; jj < 2 * Hs; jj += 256) acc += ctx[(size_t)b * 2 * Hs + jj] * Wfin[2 * Hs + jj];
  __shared__ float red[256];
  red[tid] = acc;
  __syncthreads();
  for (int off = 128; off > 0; off >>= 1) {
    if (tid < off) red[tid] += red[tid + off];
    __syncthreads();
  }
  if (tid == 0) out[b] = red[0] + bfin[0];
}

extern "C" void kernel_launch(void* const* d_in, const int* in_sizes, int n_in,
                              void* d_out, int out_size, void* d_ws, size_t ws_size,
                              hipStream_t stream) {
  const float* X     = (const float*)d_in[0];
  const float* yp    = (const float*)d_in[1];
  const float* encW  = (const float*)d_in[2];
  const float* encb  = (const float*)d_in[3];
  const float* e0Wih = (const float*)d_in[4];
  const float* e0Whh = (const float*)d_in[5];
  const float* e0bih = (const float*)d_in[6];
  const float* e0bhh = (const float*)d_in[7];
  const float* e1Wih = (const float*)d_in[8];
  const float* e1Whh = (const float*)d_in[9];
  const float* e1bih = (const float*)d_in[10];
  const float* e1bhh = (const float*)d_in[11];
  const float* dA1W  = (const float*)d_in[12];
  const float* dA2W  = (const float*)d_in[14];
  const float* dWih  = (const float*)d_in[16];
  const float* dWhh  = (const float*)d_in[17];
  const float* dbih  = (const float*)d_in[18];
  const float* dbhh  = (const float*)d_in[19];
  const float* fcW   = (const float*)d_in[20];
  const float* fcb   = (const float*)d_in[21];
  const float* WfinW = (const float*)d_in[22];
  const float* Wfinb = (const float*)d_in[23];
  float* out = (float*)d_out;
  (void)in_sizes; (void)n_in; (void)out_size; (void)ws_size;

  char* wsb = (char*)d_ws;
  size_t off = 0;
  auto alloc = [&](size_t bytes) -> void* {
    void* p = wsb + off;
    off = (off + bytes + 255) & ~(size_t)255;
    return p;
  };
  const size_t BH  = (size_t)Bsz * Hs;
  const size_t BH2 = (size_t)Bsz * 2 * Hs;
  // ---- zero-init region (one memset per call) ----
  float* c1   = (float*)alloc(BH * 4);
  float* c2   = (float*)alloc(BH * 4);
  float* cdec = (float*)alloc(BH2 * 4);
  bf16* h1hi0 = (bf16*)alloc(BH * 2);
  bf16* h2hi0 = (bf16*)alloc(BH * 2);
  bf16* dhi0  = (bf16*)alloc(BH2 * 2);
  const size_t zero_bytes = off;
  // ---- rest ----
  bf16* h1hi1 = (bf16*)alloc(BH * 2);
  bf16* h2hi1 = (bf16*)alloc(BH * 2);
  bf16* dhi1  = (bf16*)alloc(BH2 * 2);
  bf16* W0hi  = (bf16*)alloc((size_t)2048 * 544 * 2);
  bf16* W0lo  = (bf16*)alloc((size_t)2048 * 544 * 2);
  bf16* W1hi  = (bf16*)alloc((size_t)2048 * 544 * 2);
  bf16* W1lo  = (bf16*)alloc((size_t)2048 * 544 * 2);
  bf16* Wdhi  = (bf16*)alloc((size_t)4096 * 1024 * 2);
  bf16* Wdlo  = (bf16*)alloc((size_t)4096 * 1024 * 2);
  float* bs0  = (float*)alloc(2048 * 4);
  float* bs1  = (float*)alloc(2048 * 4);
  float* bsd  = (float*)alloc(4096 * 4);
  float* wihp = (float*)alloc(4096 * 4);
  bf16* x1h   = (bf16*)alloc((size_t)T1 * Bsz * 16 * 2);
  bf16* x2h   = (bf16*)alloc((size_t)T1 * Bsz * 16 * 2);
  float* Xe   = (float*)alloc((size_t)Bsz * T1 * 2 * Hs * 4);
  float* dfp  = (float*)alloc(BH2 * 4);
  float* ctx  = (float*)alloc(BH2 * 4);
  float* vv   = (float*)alloc(2 * Hs * 4);
  float* yt   = (float*)alloc((size_t)Bsz * T1 * 4);

  hipMemsetAsync(d_ws, 0, zero_bytes, stream);

  build_w_k<<<(4 * Hs * (544 / 8) + 255) / 256, 256, 0, stream>>>(
      e0Whh, e0Wih, e0bih, e0bhh, W0hi, W0lo, bs0, nullptr, Hs, 16, 544);
  build_w_k<<<(4 * Hs * (544 / 8) + 255) / 256, 256, 0, stream>>>(
      e1Whh, e1Wih, e1bih, e1bhh, W1hi, W1lo, bs1, nullptr, Hs, 15, 544);
  build_w_k<<<(8 * Hs * (1024 / 8) + 255) / 256, 256, 0, stream>>>(
      dWhh, dWih, dbih, dbhh, Wdhi, Wdlo, bsd, wihp, 2 * Hs, 0, 1024);
  prep_attn_k<<<Bsz, 64, 0, stream>>>(X, yp, encW, encb, x1h, x2h);
  prep_v_k<<<(2 * Hs) / 256, 256, 0, stream>>>(dA1W, dA2W, vv);

  // ---- encoder: 9 steps, both branches per launch ----
  bf16 *h1c = h1hi0, *h1n = h1hi1;
  bf16 *h2c = h2hi0, *h2n = h2hi1;
  for (int t = 0; t < T1; ++t) {
    GA a0{h1c, x1h + (size_t)t * Bsz * 16, W0hi, W0lo, bs0, nullptr, nullptr,
          c1, h1n, Xe + (size_t)t * 2 * Hs, T1 * 2 * Hs, 0};
    GA a1{h2c, x2h + (size_t)t * Bsz * 16, W1hi, W1lo, bs1, nullptr, nullptr,
          c2, h2n, Xe + (size_t)t * 2 * Hs + Hs, T1 * 2 * Hs, 0};
    dim3 grid((4 * Hs) / BNP, Bsz / BMT, 2);
    lstm2_k<Hs, 544, true, 2><<<grid, 256, 0, stream>>>(a0, a1);
    bf16* tp;
    tp = h1c; h1c = h1n; h1n = tp;
    tp = h2c; h2c = h2n; h2n = tp;
  }

  dec_ctx_k<<<Bsz, 256, 0, stream>>>(Xe, vv, yp, fcW, fcb, ctx, yt);

  // ---- decoder: 9 steps ----
  bf16 *dc = dhi0, *dn = dhi1;
  for (int t = 0; t < T1; ++t) {
    GA a0{dc, nullptr, Wdhi, Wdlo, bsd, wihp, yt + t,
          cdec, dn, (t == T1 - 1) ? dfp : nullptr, 2 * Hs, T1};
    dim3 grid((8 * Hs) / BNP, Bsz / BMT, 1);
    lstm2_k<2 * Hs, 1024, false, 1><<<grid, 256, 0, stream>>>(a0, a0);
    bf16* tp = dc; dc = dn; dn = tp;
  }

  final_out_k<<<Bsz, 256, 0, stream>>>(dfp, ctx, WfinW, Wfinb, out);
}